// Round 9
// baseline (63.987 us; speedup 1.0000x reference)
//
#include <hip/hip_runtime.h>

#define N 4096
#define SEG 64            // elements per lane
#define BLOCK 256         // 4 waves per workgroup
#define ROWS_PER_WAVE 2
#define LCAP 512          // int(1024 * 0.5)
#define BIG (1 << 28)

typedef int vint4 __attribute__((ext_vector_type(4)));

__device__ __forceinline__ void load_row(float4 (&buf)[16],
                                         const float* __restrict__ probs,
                                         long row, int lane) {
  const float4* p4 = (const float4*)(probs + row * (long)N + lane * SEG);
#pragma unroll
  for (int q = 0; q < 16; ++q) buf[q] = p4[q];
  __builtin_amdgcn_sched_barrier(0);   // pin the issue point; don't sink
}

__device__ __forceinline__ void process_row(const float4 (&buf)[16],
                                            int* __restrict__ out,
                                            long row, int lane) {
  // ---- Phase 1: consume buf -> packed costs cp[] + composed map (S,LO,HI)
  //      of d' = c + clamp(d,-L,L).  After this, buf is dead (regs recycle).
  int S = 0, lo = -BIG, hi = BIG;
  unsigned cp[SEG / 2];
#pragma unroll
  for (int q = 0; q < 16; ++q) {
    float pv[4] = {buf[q].x, buf[q].y, buf[q].z, buf[q].w};
#pragma unroll
    for (int e = 0; e < 2; ++e) {
      float pa = pv[2 * e], pb = pv[2 * e + 1];
      int a0 = (int)(1024.0f * pa);
      int b0 = (int)__builtin_fmaf(-1024.0f, pa, 1024.0f);  // exact: pow2 scale
      int a1 = (int)(1024.0f * pb);
      int b1 = (int)__builtin_fmaf(-1024.0f, pb, 1024.0f);
      int ca = a0 - b0, cb = a1 - b1;
      cp[q * 2 + e] = ((unsigned)ca & 0xffffu) | ((unsigned)cb << 16);
      S += ca; lo = ca + min(max(lo, -LCAP), LCAP); hi = ca + min(max(hi, -LCAP), LCAP);
      S += cb; lo = cb + min(max(lo, -LCAP), LCAP); hi = cb + min(max(hi, -LCAP), LCAP);
    }
  }

  // ---- Phase 2: exclusive wave scan of maps -> exact incoming d per lane.
  int Sx = __shfl_up(S, 1), lox = __shfl_up(lo, 1), hix = __shfl_up(hi, 1);
  if (lane == 0) { Sx = 0; lox = -BIG; hix = BIG; }
#pragma unroll
  for (int dlt = 1; dlt < 64; dlt <<= 1) {
    int Si = __shfl_up(Sx, dlt);
    int loi = __shfl_up(lox, dlt);
    int hii = __shfl_up(hix, dlt);
    if (lane >= dlt) {
      int nlo = min(max(loi + Sx, lox), hix);   // incoming applied first
      int nhi = min(max(hii + Sx, lox), hix);
      Sx = Si + Sx;
      lox = nlo; hix = nhi;
    }
  }
  int d = min(max(Sx, lox), hix);  // h(0) = clamp(S, LO, HI)

  // ---- Phase 3: replay segment, record choice bits in 64-bit masks.
  unsigned m0lo = 0, m0hi = 0, m1lo = 0, m1hi = 0;
#pragma unroll
  for (int j = 0; j < SEG; ++j) {
    int c = (int)cp[j >> 1];
    c = (j & 1) ? (c >> 16) : ((c << 16) >> 16);        // sext i16
    unsigned b0 = ((unsigned)(LCAP - d)) >> 31;          // c0: d >  L
    unsigned b1 = ((unsigned)(d + LCAP)) >> 31;          // c1: d < -L
    if (j < 32) { m0lo |= b0 << j;        m1lo |= b1 << j; }
    else        { m0hi |= b0 << (j - 32); m1hi |= b1 << (j - 32); }
    d = c + min(max(d, -LCAP), LCAP);
  }

  // final label of the whole row
  int dfin = __shfl(d, 63);
  int xfin = (dfin >= 0) ? 1 : 0;

  // ---- Phase 4: per-lane backward composite P(x) = (x|S)&~R.
  unsigned long long M0 = ((unsigned long long)m0hi << 32) | m0lo;
  unsigned long long M1 = ((unsigned long long)m1hi << 32) | m1lo;
  unsigned long long Mm = M0 | M1;
  int Sb = 0, Rb = 0;
  int ffs = __ffsll((long long)Mm);       // 0 if no force
  if (ffs) {
    int j = ffs - 1;
    Sb = (int)((M0 >> j) & 1);
    Rb = (int)((M1 >> j) & 1);
  }
  int f = Sb | (Rb << 1);

  // reverse exclusive wave scan of latch functions (higher lane applied first)
  int fx = __shfl_down(f, 1);
  if (lane == 63) fx = 0;
#pragma unroll
  for (int dlt = 1; dlt < 64; dlt <<= 1) {
    int fi = __shfl_down(fx, dlt);
    if (lane < 64 - dlt) {
      int Sp = fi & 1, Rp = (fi >> 1) & 1;   // incoming (applied first)
      int Sq = fx & 1, Rq = (fx >> 1) & 1;   // own (applied last)
      int Sn = (Sp & (Rq ^ 1)) | Sq;
      int Rn = (Rp | Rq) & (Sn ^ 1);
      fx = Sn | (Rn << 1);
    }
  }
  // x = this lane's LAST label (segment-local j=63)
  int x = (xfin | (fx & 1)) & (((fx >> 1) & 1) ^ 1);

  // ---- Phase 5: bit-parallel in-segment backtrack (Kogge-Stone fill from
  // nearest determined marker above; sentinel = x at bit 63), then fully
  // coalesced nontemporal stores (each instruction = contiguous 1KB span).
  unsigned long long Am = M0 >> 1;           // bit j: c0 at pos j+1 -> x_j = 1
  unsigned long long Bm = M1 >> 1;           // bit j: c1 at pos j+1 -> x_j = 0
  unsigned long long D = Am | Bm | (1ull << 63);
  unsigned long long V = Am | ((unsigned long long)(unsigned)x << 63);
#pragma unroll
  for (int s = 1; s < 64; s <<= 1) {
    unsigned long long nd = (D >> s) & ~D;   // newly determined this step
    V |= (V >> s) & nd;
    D |= (D >> s);
  }
  // V bit j = label of local position j

  int* __restrict__ orow0 = out + row * (long)N;
#pragma unroll
  for (int c = 0; c < 16; ++c) {
    int src = 4 * c + (lane >> 4);
    unsigned long long m = (unsigned long long)__shfl((long long)V, src);
    unsigned nib = (unsigned)(m >> ((lane & 15) * 4)) & 0xFu;
    vint4 v = {(int)(nib & 1u), (int)((nib >> 1) & 1u),
               (int)((nib >> 2) & 1u), (int)((nib >> 3) & 1u)};
    __builtin_nontemporal_store(v, (vint4*)(orow0 + c * 256) + lane);
  }
}

__global__ __launch_bounds__(BLOCK, 4) void binarize_kernel(
    const float* __restrict__ probs, int* __restrict__ out) {
  const int lane = threadIdx.x & 63;
  const int wid = threadIdx.x >> 6;
  const long row0 = ((long)blockIdx.x * 4 + wid) * ROWS_PER_WAVE;

  // Flattened static double-buffer: row1's loads issue a full row-process
  // ahead of use; 4096 waves (4/SIMD) interleave compute with memory waits.
  float4 A[16], B[16];
  load_row(A, probs, row0 + 0, lane);
  load_row(B, probs, row0 + 1, lane);
  process_row(A, out, row0 + 0, lane);
  process_row(B, out, row0 + 1, lane);
}

extern "C" void kernel_launch(void* const* d_in, const int* in_sizes, int n_in,
                              void* d_out, int out_size, void* d_ws, size_t ws_size,
                              hipStream_t stream) {
  const float* probs = (const float*)d_in[0];
  int* out = (int*)d_out;
  const int B = in_sizes[0] / N;                     // 8192 rows
  const int grid = B / (4 * ROWS_PER_WAVE);          // 1024 blocks, 4096 waves
  binarize_kernel<<<grid, BLOCK, 0, stream>>>(probs, out);
}

// Round 10
// 46.805 us; speedup vs baseline: 1.3671x; 1.3671x over previous
//
#include <hip/hip_runtime.h>

#define N 4096
#define SEG 64            // elements per lane
#define BLOCK 256         // 4 waves per workgroup
#define ROWS_PER_WAVE 2
#define LCAP 512          // int(1024 * 0.5)
#define BIG (1 << 28)

typedef int vint4 __attribute__((ext_vector_type(4)));

__device__ __forceinline__ void load_row(float4 (&buf)[16],
                                         const float* __restrict__ probs,
                                         long row, int lane) {
  const float4* p4 = (const float4*)(probs + row * (long)N + lane * SEG);
#pragma unroll
  for (int q = 0; q < 16; ++q) buf[q] = p4[q];
  __builtin_amdgcn_sched_barrier(0);   // pin the issue point; don't sink
}

__device__ __forceinline__ void process_row(const float4 (&buf)[16],
                                            int* __restrict__ out,
                                            long row, int lane) {
  // ---- Phase 1: consume buf -> packed costs cp[] + composed map (S,LO,HI)
  //      of d' = c + clamp(d,-L,L).  After this, buf is dead (regs recycle).
  int S = 0, lo = -BIG, hi = BIG;
  unsigned cp[SEG / 2];
#pragma unroll
  for (int q = 0; q < 16; ++q) {
    float pv[4] = {buf[q].x, buf[q].y, buf[q].z, buf[q].w};
#pragma unroll
    for (int e = 0; e < 2; ++e) {
      float pa = pv[2 * e], pb = pv[2 * e + 1];
      int a0 = (int)(1024.0f * pa);
      int b0 = (int)__builtin_fmaf(-1024.0f, pa, 1024.0f);  // exact: pow2 scale
      int a1 = (int)(1024.0f * pb);
      int b1 = (int)__builtin_fmaf(-1024.0f, pb, 1024.0f);
      int ca = a0 - b0, cb = a1 - b1;
      cp[q * 2 + e] = ((unsigned)ca & 0xffffu) | ((unsigned)cb << 16);
      S += ca; lo = ca + min(max(lo, -LCAP), LCAP); hi = ca + min(max(hi, -LCAP), LCAP);
      S += cb; lo = cb + min(max(lo, -LCAP), LCAP); hi = cb + min(max(hi, -LCAP), LCAP);
    }
  }

  // ---- Phase 2: exclusive wave scan of maps -> exact incoming d per lane.
  int Sx = __shfl_up(S, 1), lox = __shfl_up(lo, 1), hix = __shfl_up(hi, 1);
  if (lane == 0) { Sx = 0; lox = -BIG; hix = BIG; }
#pragma unroll
  for (int dlt = 1; dlt < 64; dlt <<= 1) {
    int Si = __shfl_up(Sx, dlt);
    int loi = __shfl_up(lox, dlt);
    int hii = __shfl_up(hix, dlt);
    if (lane >= dlt) {
      int nlo = min(max(loi + Sx, lox), hix);   // incoming applied first
      int nhi = min(max(hii + Sx, lox), hix);
      Sx = Si + Sx;
      lox = nlo; hix = nhi;
    }
  }
  int d = min(max(Sx, lox), hix);  // h(0) = clamp(S, LO, HI)

  // ---- Phase 3: replay segment, record choice bits in 64-bit masks.
  unsigned m0lo = 0, m0hi = 0, m1lo = 0, m1hi = 0;
#pragma unroll
  for (int j = 0; j < SEG; ++j) {
    int c = (int)cp[j >> 1];
    c = (j & 1) ? (c >> 16) : ((c << 16) >> 16);        // sext i16
    unsigned b0 = ((unsigned)(LCAP - d)) >> 31;          // c0: d >  L
    unsigned b1 = ((unsigned)(d + LCAP)) >> 31;          // c1: d < -L
    if (j < 32) { m0lo |= b0 << j;        m1lo |= b1 << j; }
    else        { m0hi |= b0 << (j - 32); m1hi |= b1 << (j - 32); }
    d = c + min(max(d, -LCAP), LCAP);
  }

  // final label of the whole row
  int dfin = __shfl(d, 63);
  int xfin = (dfin >= 0) ? 1 : 0;

  // ---- Phase 4: per-lane backward composite P(x) = (x|S)&~R.
  unsigned long long M0 = ((unsigned long long)m0hi << 32) | m0lo;
  unsigned long long M1 = ((unsigned long long)m1hi << 32) | m1lo;
  unsigned long long Mm = M0 | M1;
  int Sb = 0, Rb = 0;
  int ffs = __ffsll((long long)Mm);       // 0 if no force
  if (ffs) {
    int j = ffs - 1;
    Sb = (int)((M0 >> j) & 1);
    Rb = (int)((M1 >> j) & 1);
  }
  int f = Sb | (Rb << 1);

  // reverse exclusive wave scan of latch functions (higher lane applied first)
  int fx = __shfl_down(f, 1);
  if (lane == 63) fx = 0;
#pragma unroll
  for (int dlt = 1; dlt < 64; dlt <<= 1) {
    int fi = __shfl_down(fx, dlt);
    if (lane < 64 - dlt) {
      int Sp = fi & 1, Rp = (fi >> 1) & 1;   // incoming (applied first)
      int Sq = fx & 1, Rq = (fx >> 1) & 1;   // own (applied last)
      int Sn = (Sp & (Rq ^ 1)) | Sq;
      int Rn = (Rp | Rq) & (Sn ^ 1);
      fx = Sn | (Rn << 1);
    }
  }
  // x = this lane's LAST label (segment-local j=63)
  int x = (xfin | (fx & 1)) & (((fx >> 1) & 1) ^ 1);

  // ---- Phase 5: bit-parallel in-segment backtrack (Kogge-Stone fill from
  // nearest determined marker above; sentinel = x at bit 63), then fully
  // coalesced nontemporal stores (each instruction = contiguous 1KB span).
  unsigned long long Am = M0 >> 1;           // bit j: c0 at pos j+1 -> x_j = 1
  unsigned long long Bm = M1 >> 1;           // bit j: c1 at pos j+1 -> x_j = 0
  unsigned long long D = Am | Bm | (1ull << 63);
  unsigned long long V = Am | ((unsigned long long)(unsigned)x << 63);
#pragma unroll
  for (int s = 1; s < 64; s <<= 1) {
    unsigned long long nd = (D >> s) & ~D;   // newly determined this step
    V |= (V >> s) & nd;
    D |= (D >> s);
  }
  // V bit j = label of local position j

  int* __restrict__ orow0 = out + row * (long)N;
#pragma unroll
  for (int c = 0; c < 16; ++c) {
    int src = 4 * c + (lane >> 4);
    unsigned long long m = (unsigned long long)__shfl((long long)V, src);
    unsigned nib = (unsigned)(m >> ((lane & 15) * 4)) & 0xFu;
    vint4 v = {(int)(nib & 1u), (int)((nib >> 1) & 1u),
               (int)((nib >> 2) & 1u), (int)((nib >> 3) & 1u)};
    __builtin_nontemporal_store(v, (vint4*)(orow0 + c * 256) + lane);
  }
}

__global__ __launch_bounds__(BLOCK, 2) void binarize_kernel(
    const float* __restrict__ probs, int* __restrict__ out) {
  const int lane = threadIdx.x & 63;
  const int wid = threadIdx.x >> 6;
  const long row0 = ((long)blockIdx.x * 4 + wid) * ROWS_PER_WAVE;

  // Flattened static double-buffer (proven to fit in 96 VGPRs at cap 256):
  // row1's loads issue a full row-process ahead of use; 4096 waves (4/SIMD,
  // register-permitted at 96 VGPR) interleave compute with memory waits.
  float4 A[16], B[16];
  load_row(A, probs, row0 + 0, lane);
  load_row(B, probs, row0 + 1, lane);
  process_row(A, out, row0 + 0, lane);
  process_row(B, out, row0 + 1, lane);
}

extern "C" void kernel_launch(void* const* d_in, const int* in_sizes, int n_in,
                              void* d_out, int out_size, void* d_ws, size_t ws_size,
                              hipStream_t stream) {
  const float* probs = (const float*)d_in[0];
  int* out = (int*)d_out;
  const int B = in_sizes[0] / N;                     // 8192 rows
  const int grid = B / (4 * ROWS_PER_WAVE);          // 1024 blocks, 4096 waves
  binarize_kernel<<<grid, BLOCK, 0, stream>>>(probs, out);
}